// Round 1
// baseline (3324.763 us; speedup 1.0000x reference)
//
#include <hip/hip_runtime.h>
#include <cstdint>

#define T_DIM 512
#define B_DIM 256
#define F_DIM 513
#define DX    256
#define H_DIM 128
#define G4    512
#define Z_DIM 16
#define ZG_D  32
#define DZX_D 128
#define M_ROWS (B_DIM * T_DIM)   // 131072

__device__ __forceinline__ float fast_tanh(float x) {
    return 1.0f - 2.0f / (__expf(2.0f * x) + 1.0f);
}
__device__ __forceinline__ float fast_sig(float x) {
    return 1.0f / (1.0f + __expf(-x));
}

__global__ void bias_comb_kernel(const float* __restrict__ a,
                                 const float* __restrict__ b,
                                 float* __restrict__ c) {
    int i = threadIdx.x;
    if (i < G4) c[i] = a[i] + b[i];
}

// Generic tiled fp32 GEMM:  C[m,n] = act(sum_k A[m,k] * W[n,k] + bias[n])
// ACT: 0 none, 1 tanh, 2 exp
// AMODE: 0 contiguous row-major [M,K] (requires K%16==0), 1 x-gather A[m,k]=x[b,k,t], m=b*T+t
// CMODE: 0 contiguous [M,N], 1 transposed out[b,n,t]
// GUARD: scalar+bounds-guarded W loads (K edge or N edge)
template<int ACT, int AMODE, int CMODE, bool GUARD>
__global__ __launch_bounds__(256) void gemm_kernel(
    const float* __restrict__ A, const float* __restrict__ W,
    const float* __restrict__ bias, float* __restrict__ C,
    int M, int N, int K)
{
    __shared__ float As[16][68];
    __shared__ float Bs[16][68];
    const int tid = threadIdx.x;
    const int m0 = blockIdx.y * 64;
    const int n0 = blockIdx.x * 64;
    const int tm = tid >> 4;   // 0..15
    const int tn = tid & 15;   // 0..15
    float acc[4][4] = {};
    const int kTiles = (K + 15) >> 4;
    for (int kt = 0; kt < kTiles; ++kt) {
        const int k0 = kt << 4;
        // ---- load A tile (transposed into LDS: As[k][m]) ----
        if (AMODE == 0) {
            const int m  = tid >> 2;      // 0..63
            const int kq = tid & 3;       // 0..3
            const float4 v = *(const float4*)&A[(size_t)(m0 + m) * K + k0 + kq * 4];
            As[kq * 4 + 0][m] = v.x; As[kq * 4 + 1][m] = v.y;
            As[kq * 4 + 2][m] = v.z; As[kq * 4 + 3][m] = v.w;
        } else {
            const int m  = tid & 63;
            const int kq = tid >> 6;      // 0..3
            const int mg = m0 + m;
            const int bb = mg >> 9;       // /T
            const int tt = mg & 511;      // %T
            const size_t base = (size_t)bb * (F_DIM * T_DIM) + tt;
            #pragma unroll
            for (int j = 0; j < 4; ++j) {
                const int k = k0 + kq * 4 + j;
                As[kq * 4 + j][m] = (k < K) ? A[base + (size_t)k * T_DIM] : 0.0f;
            }
        }
        // ---- load W tile (Bs[k][n]) ----
        {
            const int n  = tid >> 2;
            const int kq = tid & 3;
            const int ng = n0 + n;
            if (!GUARD) {
                const float4 v = *(const float4*)&W[(size_t)ng * K + k0 + kq * 4];
                Bs[kq * 4 + 0][n] = v.x; Bs[kq * 4 + 1][n] = v.y;
                Bs[kq * 4 + 2][n] = v.z; Bs[kq * 4 + 3][n] = v.w;
            } else {
                #pragma unroll
                for (int j = 0; j < 4; ++j) {
                    const int k = k0 + kq * 4 + j;
                    float v = 0.0f;
                    if (ng < N && k < K) v = W[(size_t)ng * K + k];
                    Bs[kq * 4 + j][n] = v;
                }
            }
        }
        __syncthreads();
        #pragma unroll
        for (int kk = 0; kk < 16; ++kk) {
            const float4 av = *(const float4*)&As[kk][tm * 4];
            const float4 bv = *(const float4*)&Bs[kk][tn * 4];
            const float a0 = av.x, a1 = av.y, a2 = av.z, a3 = av.w;
            const float b0 = bv.x, b1 = bv.y, b2 = bv.z, b3 = bv.w;
            acc[0][0] += a0 * b0; acc[0][1] += a0 * b1; acc[0][2] += a0 * b2; acc[0][3] += a0 * b3;
            acc[1][0] += a1 * b0; acc[1][1] += a1 * b1; acc[1][2] += a1 * b2; acc[1][3] += a1 * b3;
            acc[2][0] += a2 * b0; acc[2][1] += a2 * b1; acc[2][2] += a2 * b2; acc[2][3] += a2 * b3;
            acc[3][0] += a3 * b0; acc[3][1] += a3 * b1; acc[3][2] += a3 * b2; acc[3][3] += a3 * b3;
        }
        __syncthreads();
    }
    // ---- epilogue ----
    #pragma unroll
    for (int i = 0; i < 4; ++i) {
        const int m = m0 + tm * 4 + i;
        if (CMODE == 0) {
            float r[4];
            #pragma unroll
            for (int j = 0; j < 4; ++j) {
                const int n = n0 + tn * 4 + j;
                float v = acc[i][j] + bias[n];
                if (ACT == 1) v = fast_tanh(v);
                else if (ACT == 2) v = __expf(v);
                r[j] = v;
            }
            *(float4*)&C[(size_t)m * N + n0 + tn * 4] = make_float4(r[0], r[1], r[2], r[3]);
        } else {
            const int bb = m >> 9;
            const int tt = m & 511;
            #pragma unroll
            for (int j = 0; j < 4; ++j) {
                const int n = n0 + tn * 4 + j;
                if (n < N) {
                    float v = acc[i][j] + bias[n];
                    if (ACT == 1) v = fast_tanh(v);
                    else if (ACT == 2) v = __expf(v);
                    C[(size_t)bb * (F_DIM * T_DIM) + (size_t)n * T_DIM + tt] = v;
                }
            }
        }
    }
}

// Backward LSTM: one block per batch row b; W_hh rows held in registers (2 rows/thread).
// gin layout [B, T, 512] (b_ih+b_hh already folded in). g_out layout [B, T, 128].
__global__ __launch_bounds__(256, 1) void lstm_kernel(
    const float* __restrict__ gin,
    const float* __restrict__ W_hh,   // [512,128]
    float* __restrict__ g_out)
{
    __shared__ float4 h4[32];         // h, 128 floats
    __shared__ float gates[512];
    const int tid = threadIdx.x;
    const int b = blockIdx.x;

    float4 wA[32], wB[32];
    const float4* w4 = (const float4*)W_hh;
    #pragma unroll
    for (int q = 0; q < 32; ++q) {
        wA[q] = w4[(size_t)(2 * tid) * 32 + q];
        wB[q] = w4[(size_t)(2 * tid + 1) * 32 + q];
    }
    if (tid < 32) h4[tid] = make_float4(0.f, 0.f, 0.f, 0.f);
    float c = 0.0f;
    __syncthreads();

    const float2* gin2 = (const float2*)(gin + (size_t)b * T_DIM * G4);
    float2 gv = gin2[(size_t)(T_DIM - 1) * 256 + tid];
    for (int t = T_DIM - 1; t >= 0; --t) {
        float2 gnext = (t > 0) ? gin2[(size_t)(t - 1) * 256 + tid] : make_float2(0.f, 0.f);
        float a0 = 0.f, a1 = 0.f;
        #pragma unroll
        for (int q = 0; q < 32; ++q) {
            const float4 hv = h4[q];
            a0 += wA[q].x * hv.x + wA[q].y * hv.y + wA[q].z * hv.z + wA[q].w * hv.w;
            a1 += wB[q].x * hv.x + wB[q].y * hv.y + wB[q].z * hv.z + wB[q].w * hv.w;
        }
        a0 += gv.x;
        a1 += gv.y;
        gates[2 * tid]     = a0;
        gates[2 * tid + 1] = a1;
        __syncthreads();
        if (tid < 128) {
            const float iv = gates[tid];
            const float fv = gates[tid + 128];
            const float gg = gates[tid + 256];
            const float ov = gates[tid + 384];
            c = fast_sig(fv) * c + fast_sig(iv) * fast_tanh(gg);
            const float h = fast_sig(ov) * fast_tanh(c);
            ((float*)h4)[tid] = h;
            g_out[((size_t)b * T_DIM + t) * H_DIM + tid] = h;
        }
        __syncthreads();
        gv = gnext;
    }
}

// Inference scan: one block (1 wave, 64 lanes) per batch row. All weights in registers.
// g layout [B,T,128], eps layout [T,B,16], z_out layout [B,T,16].
__global__ __launch_bounds__(64, 1) void infer_kernel(
    const float* __restrict__ g,
    const float* __restrict__ eps,
    const float* __restrict__ W_zg0, const float* __restrict__ b_zg0,
    const float* __restrict__ W_zg1, const float* __restrict__ b_zg1,
    const float* __restrict__ W_im,  const float* __restrict__ b_im,
    const float* __restrict__ W_il,  const float* __restrict__ b_il,
    float* __restrict__ z_out)
{
    __shared__ float zbuf[16];
    __shared__ float hzbuf[32];
    __shared__ float h2buf[128];
    const int l = threadIdx.x;
    const int b = blockIdx.x;

    // stage-1 weights: W_zg0 row (l&31), 16 wide
    const int r0 = l & 31;
    float4 wz0[4];
    #pragma unroll
    for (int q = 0; q < 4; ++q) wz0[q] = ((const float4*)W_zg0)[r0 * 4 + q];
    const float bz0 = b_zg0[r0];
    // stage-2 weights: W_zg1 rows l and l+64, 32 wide each
    float4 w1a[8], w1b[8];
    #pragma unroll
    for (int q = 0; q < 8; ++q) {
        w1a[q] = ((const float4*)W_zg1)[l * 8 + q];
        w1b[q] = ((const float4*)W_zg1)[(l + 64) * 8 + q];
    }
    const float bz1a = b_zg1[l], bz1b = b_zg1[l + 64];
    // stage-3 weights: output o=l&31 (o<16: zm row o; else zl row o-16), k half = l>>5
    const int o = l & 31;
    const int half = l >> 5;
    const float* w3p = (o < 16) ? (W_im + o * 128) : (W_il + (o - 16) * 128);
    float4 w3[16];
    #pragma unroll
    for (int q = 0; q < 16; ++q) w3[q] = ((const float4*)(w3p + half * 64))[q];
    const float b3 = (o < 16) ? b_im[o] : b_il[o - 16];

    if (l < 16) zbuf[l] = 0.0f;
    __syncthreads();

    const float* gb = g + (size_t)b * T_DIM * 128;
    float ngl0 = gb[l];
    float ngl1 = gb[64 + l];
    float neps = (l < 16) ? eps[(size_t)b * 16 + l] : 0.0f;
    for (int t = 0; t < T_DIM; ++t) {
        const float gl0 = ngl0, gl1 = ngl1, epsv = neps;
        if (t + 1 < T_DIM) {
            ngl0 = gb[(size_t)(t + 1) * 128 + l];
            ngl1 = gb[(size_t)(t + 1) * 128 + 64 + l];
            neps = (l < 16) ? eps[((size_t)(t + 1) * B_DIM + b) * 16 + l] : 0.0f;
        }
        // stage 1: hz = tanh(W_zg0 @ z + b_zg0), lanes 0..31
        float s1 = bz0;
        {
            const float4* z4 = (const float4*)zbuf;
            #pragma unroll
            for (int q = 0; q < 4; ++q) {
                const float4 zv = z4[q];
                s1 += wz0[q].x * zv.x + wz0[q].y * zv.y + wz0[q].z * zv.z + wz0[q].w * zv.w;
            }
        }
        const float hz = fast_tanh(s1);
        __syncthreads();
        if (l < 32) hzbuf[l] = hz;
        __syncthreads();
        // stage 2: hz2 = tanh(W_zg1 @ hz + b_zg1); g_t = 0.5*(hz2 + g_rnn)
        float s2a = bz1a, s2b = bz1b;
        {
            const float4* hz4 = (const float4*)hzbuf;
            #pragma unroll
            for (int q = 0; q < 8; ++q) {
                const float4 hv = hz4[q];
                s2a += w1a[q].x * hv.x + w1a[q].y * hv.y + w1a[q].z * hv.z + w1a[q].w * hv.w;
                s2b += w1b[q].x * hv.x + w1b[q].y * hv.y + w1b[q].z * hv.z + w1b[q].w * hv.w;
            }
        }
        const float gt0 = 0.5f * (fast_tanh(s2a) + gl0);
        const float gt1 = 0.5f * (fast_tanh(s2b) + gl1);
        __syncthreads();
        h2buf[l]      = gt0;
        h2buf[l + 64] = gt1;
        __syncthreads();
        // stage 3: zm/zl dot-128, split over lane pairs (l, l^32), outputs o=l&31
        float s3 = 0.0f;
        {
            const float4* h24 = (const float4*)(h2buf + half * 64);
            #pragma unroll
            for (int q = 0; q < 16; ++q) {
                const float4 hv = h24[q];
                s3 += w3[q].x * hv.x + w3[q].y * hv.y + w3[q].z * hv.z + w3[q].w * hv.w;
            }
        }
        const float full = s3 + __shfl_xor(s3, 32, 64);
        const float val = full + b3;                 // o<16: zm[o], o>=16: zl[o-16]
        const float other = __shfl_xor(val, 16, 64); // for l<16: zl[l]
        const float znew = val + epsv * __expf(0.5f * other);
        __syncthreads();
        if (l < 16) {
            zbuf[l] = znew;
            z_out[((size_t)b * T_DIM + t) * 16 + l] = znew;
        }
        __syncthreads();
    }
}

extern "C" void kernel_launch(void* const* d_in, const int* in_sizes, int n_in,
                              void* d_out, int out_size, void* d_ws, size_t ws_size,
                              hipStream_t stream)
{
    const float* x     = (const float*)d_in[0];
    const float* eps   = (const float*)d_in[1];
    const float* W_xg  = (const float*)d_in[2];
    const float* b_xg  = (const float*)d_in[3];
    const float* W_ih  = (const float*)d_in[4];
    const float* W_hh  = (const float*)d_in[5];
    const float* b_ih  = (const float*)d_in[6];
    const float* b_hh  = (const float*)d_in[7];
    const float* W_zg0 = (const float*)d_in[8];
    const float* b_zg0 = (const float*)d_in[9];
    const float* W_zg1 = (const float*)d_in[10];
    const float* b_zg1 = (const float*)d_in[11];
    const float* W_im  = (const float*)d_in[12];
    const float* b_im  = (const float*)d_in[13];
    const float* W_il  = (const float*)d_in[14];
    const float* b_il  = (const float*)d_in[15];
    // 16..27: gate/prop/pm/pl weights — dead code (outputs unused by reference return)
    const float* W_zx0 = (const float*)d_in[28];
    const float* b_zx0 = (const float*)d_in[29];
    const float* W_zx1 = (const float*)d_in[30];
    const float* b_zx1 = (const float*)d_in[31];
    const float* W_gy  = (const float*)d_in[32];
    const float* b_gy  = (const float*)d_in[33];
    float* out = (float*)d_out;
    float* ws  = (float*)d_ws;

    // workspace layout (floats)
    float* xg  = ws;                        // 131072*256 = 33,554,432
    float* gin = ws + 33554432ull;          // 131072*512 = 67,108,864
    float* g   = ws + 100663296ull;         // 131072*128 = 16,777,216
    float* z   = ws + 117440512ull;         // 131072*16  =  2,097,152
    float* bc  = ws + 119537664ull;         // 512
    float* hy1 = ws;                        // alias xg (dead after G2)
    float* hy2 = ws + 16777216ull;          // alias xg upper half

    bias_comb_kernel<<<1, 512, 0, stream>>>(b_ih, b_hh, bc);
    // G1: xg = tanh(xs @ W_xg.T + b_xg), m = b*T+t, A = x gather, K=513
    gemm_kernel<1, 1, 0, true><<<dim3(DX / 64, M_ROWS / 64), 256, 0, stream>>>(
        x, W_xg, b_xg, xg, M_ROWS, DX, F_DIM);
    // G2: gin = xg @ W_ih.T + (b_ih + b_hh), K=256, N=512
    gemm_kernel<0, 0, 0, false><<<dim3(G4 / 64, M_ROWS / 64), 256, 0, stream>>>(
        xg, W_ih, bc, gin, M_ROWS, G4, DX);
    // backward LSTM scan -> g
    lstm_kernel<<<B_DIM, 256, 0, stream>>>(gin, W_hh, g);
    // inference scan -> z
    infer_kernel<<<B_DIM, 64, 0, stream>>>(g, eps, W_zg0, b_zg0, W_zg1, b_zg1,
                                           W_im, b_im, W_il, b_il, z);
    // y path
    gemm_kernel<1, 0, 0, false><<<dim3(DZX_D / 64, M_ROWS / 64), 256, 0, stream>>>(
        z, W_zx0, b_zx0, hy1, M_ROWS, DZX_D, Z_DIM);
    gemm_kernel<1, 0, 0, false><<<dim3(DZX_D / 64, M_ROWS / 64), 256, 0, stream>>>(
        hy1, W_zx1, b_zx1, hy2, M_ROWS, DZX_D, DZX_D);
    gemm_kernel<2, 0, 1, true><<<dim3(9, M_ROWS / 64), 256, 0, stream>>>(
        hy2, W_gy, b_gy, out, M_ROWS, F_DIM, DZX_D);
}

// Round 2
// 3282.682 us; speedup vs baseline: 1.0128x; 1.0128x over previous
//
#include <hip/hip_runtime.h>
#include <cstdint>

#define T_DIM 512
#define B_DIM 256
#define F_DIM 513
#define DX    256
#define H_DIM 128
#define G4    512
#define Z_DIM 16
#define ZG_D  32
#define DZX_D 128
#define M_ROWS (B_DIM * T_DIM)   // 131072

__device__ __forceinline__ float fast_tanh(float x) {
    return 1.0f - 2.0f / (__expf(2.0f * x) + 1.0f);
}
__device__ __forceinline__ float fast_sig(float x) {
    return 1.0f / (1.0f + __expf(-x));
}

__global__ void bias_comb_kernel(const float* __restrict__ a,
                                 const float* __restrict__ b,
                                 float* __restrict__ c) {
    int i = threadIdx.x;
    if (i < G4) c[i] = a[i] + b[i];
}

// Generic tiled fp32 GEMM:  C[m,n] = act(sum_k A[m,k] * W[n,k] + bias[n])
// ACT: 0 none, 1 tanh, 2 exp
// AMODE: 0 contiguous row-major [M,K] (requires K%16==0), 1 x-gather A[m,k]=x[b,k,t], m=b*T+t
// CMODE: 0 contiguous [M,N], 1 transposed out[b,n,t]
// GUARD: scalar+bounds-guarded W loads (K edge or N edge)
template<int ACT, int AMODE, int CMODE, bool GUARD>
__global__ __launch_bounds__(256) void gemm_kernel(
    const float* __restrict__ A, const float* __restrict__ W,
    const float* __restrict__ bias, float* __restrict__ C,
    int M, int N, int K)
{
    __shared__ float As[16][68];
    __shared__ float Bs[16][68];
    const int tid = threadIdx.x;
    const int m0 = blockIdx.y * 64;
    const int n0 = blockIdx.x * 64;
    const int tm = tid >> 4;   // 0..15
    const int tn = tid & 15;   // 0..15
    float acc[4][4] = {};
    const int kTiles = (K + 15) >> 4;
    for (int kt = 0; kt < kTiles; ++kt) {
        const int k0 = kt << 4;
        // ---- load A tile (transposed into LDS: As[k][m]) ----
        if (AMODE == 0) {
            const int m  = tid >> 2;      // 0..63
            const int kq = tid & 3;       // 0..3
            const float4 v = *(const float4*)&A[(size_t)(m0 + m) * K + k0 + kq * 4];
            As[kq * 4 + 0][m] = v.x; As[kq * 4 + 1][m] = v.y;
            As[kq * 4 + 2][m] = v.z; As[kq * 4 + 3][m] = v.w;
        } else {
            const int m  = tid & 63;
            const int kq = tid >> 6;      // 0..3
            const int mg = m0 + m;
            const int bb = mg >> 9;       // /T
            const int tt = mg & 511;      // %T
            const size_t base = (size_t)bb * (F_DIM * T_DIM) + tt;
            #pragma unroll
            for (int j = 0; j < 4; ++j) {
                const int k = k0 + kq * 4 + j;
                As[kq * 4 + j][m] = (k < K) ? A[base + (size_t)k * T_DIM] : 0.0f;
            }
        }
        // ---- load W tile (Bs[k][n]) ----
        {
            const int n  = tid >> 2;
            const int kq = tid & 3;
            const int ng = n0 + n;
            if (!GUARD) {
                const float4 v = *(const float4*)&W[(size_t)ng * K + k0 + kq * 4];
                Bs[kq * 4 + 0][n] = v.x; Bs[kq * 4 + 1][n] = v.y;
                Bs[kq * 4 + 2][n] = v.z; Bs[kq * 4 + 3][n] = v.w;
            } else {
                #pragma unroll
                for (int j = 0; j < 4; ++j) {
                    const int k = k0 + kq * 4 + j;
                    float v = 0.0f;
                    if (ng < N && k < K) v = W[(size_t)ng * K + k];
                    Bs[kq * 4 + j][n] = v;
                }
            }
        }
        __syncthreads();
        #pragma unroll
        for (int kk = 0; kk < 16; ++kk) {
            const float4 av = *(const float4*)&As[kk][tm * 4];
            const float4 bv = *(const float4*)&Bs[kk][tn * 4];
            const float a0 = av.x, a1 = av.y, a2 = av.z, a3 = av.w;
            const float b0 = bv.x, b1 = bv.y, b2 = bv.z, b3 = bv.w;
            acc[0][0] += a0 * b0; acc[0][1] += a0 * b1; acc[0][2] += a0 * b2; acc[0][3] += a0 * b3;
            acc[1][0] += a1 * b0; acc[1][1] += a1 * b1; acc[1][2] += a1 * b2; acc[1][3] += a1 * b3;
            acc[2][0] += a2 * b0; acc[2][1] += a2 * b1; acc[2][2] += a2 * b2; acc[2][3] += a2 * b3;
            acc[3][0] += a3 * b0; acc[3][1] += a3 * b1; acc[3][2] += a3 * b2; acc[3][3] += a3 * b3;
        }
        __syncthreads();
    }
    // ---- epilogue ----
    #pragma unroll
    for (int i = 0; i < 4; ++i) {
        const int m = m0 + tm * 4 + i;
        if (CMODE == 0) {
            float r[4];
            #pragma unroll
            for (int j = 0; j < 4; ++j) {
                const int n = n0 + tn * 4 + j;
                float v = acc[i][j] + bias[n];
                if (ACT == 1) v = fast_tanh(v);
                else if (ACT == 2) v = __expf(v);
                r[j] = v;
            }
            *(float4*)&C[(size_t)m * N + n0 + tn * 4] = make_float4(r[0], r[1], r[2], r[3]);
        } else {
            const int bb = m >> 9;
            const int tt = m & 511;
            #pragma unroll
            for (int j = 0; j < 4; ++j) {
                const int n = n0 + tn * 4 + j;
                if (n < N) {
                    float v = acc[i][j] + bias[n];
                    if (ACT == 1) v = fast_tanh(v);
                    else if (ACT == 2) v = __expf(v);
                    C[(size_t)bb * (F_DIM * T_DIM) + (size_t)n * T_DIM + tt] = v;
                }
            }
        }
    }
}

// Backward LSTM, in-wave restructure: one block per batch row b, 256 threads.
// Thread (wave w, lane l): h-index j = w*32 + (l&31), K-half kh = l>>5.
// Computes partial dots for ALL FOUR gates of index j over its K-half (4 chains
// of depth 64), combines across K-halves with __shfl_xor(.,32) (in-wave),
// computes the gate nonlinearity redundantly in both halves, writes h via a
// double-buffered LDS h (ONE barrier per step).
// gin layout [B, T, 512] (b_ih+b_hh folded). g_out layout [B, T, 128].
__global__ __launch_bounds__(256, 1) void lstm_kernel(
    const float* __restrict__ gin,
    const float* __restrict__ W_hh,   // [512,128] row-major
    float* __restrict__ g_out)
{
    __shared__ float hbuf[2][128];
    const int tid = threadIdx.x;
    const int b = blockIdx.x;
    const int lane = tid & 63;
    const int w = tid >> 6;               // wave 0..3
    const int j = w * 32 + (lane & 31);   // h index 0..127
    const int kh = lane >> 5;             // K-half 0/1

    // weights: rows j, j+128, j+256, j+384, cols [kh*64, kh*64+64)
    float4 wi[16], wf[16], wg[16], wo[16];
    {
        const float4* w4 = (const float4*)W_hh;
        const int cb = kh * 16;           // float4 col base
        #pragma unroll
        for (int q = 0; q < 16; ++q) {
            wi[q] = w4[(size_t)(j      ) * 32 + cb + q];
            wf[q] = w4[(size_t)(j + 128) * 32 + cb + q];
            wg[q] = w4[(size_t)(j + 256) * 32 + cb + q];
            wo[q] = w4[(size_t)(j + 384) * 32 + cb + q];
        }
    }
    if (tid < 128) { hbuf[0][tid] = 0.f; hbuf[1][tid] = 0.f; }
    float c = 0.0f;
    __syncthreads();

    const float* ginb = gin + (size_t)b * T_DIM * G4;
    // prefetch gates input for t = T-1
    float gi = ginb[(size_t)(T_DIM - 1) * G4 + j];
    float gf = ginb[(size_t)(T_DIM - 1) * G4 + j + 128];
    float gg = ginb[(size_t)(T_DIM - 1) * G4 + j + 256];
    float go = ginb[(size_t)(T_DIM - 1) * G4 + j + 384];

    int buf = 0;   // h state consumed at current step lives in hbuf[buf]
    for (int t = T_DIM - 1; t >= 0; --t) {
        float ngi = 0.f, ngf = 0.f, ngg = 0.f, ngo = 0.f;
        if (t > 0) {
            const size_t base = (size_t)(t - 1) * G4;
            ngi = ginb[base + j];
            ngf = ginb[base + j + 128];
            ngg = ginb[base + j + 256];
            ngo = ginb[base + j + 384];
        }
        float si = 0.f, sf = 0.f, sg = 0.f, so = 0.f;
        {
            const float4* h4 = (const float4*)&hbuf[buf][kh * 64];
            #pragma unroll
            for (int q = 0; q < 16; ++q) {
                const float4 hv = h4[q];
                si += wi[q].x * hv.x + wi[q].y * hv.y + wi[q].z * hv.z + wi[q].w * hv.w;
                sf += wf[q].x * hv.x + wf[q].y * hv.y + wf[q].z * hv.z + wf[q].w * hv.w;
                sg += wg[q].x * hv.x + wg[q].y * hv.y + wg[q].z * hv.z + wg[q].w * hv.w;
                so += wo[q].x * hv.x + wo[q].y * hv.y + so * 0.f + wo[q].w * hv.w + wo[q].z * hv.z;
            }
        }
        si += __shfl_xor(si, 32, 64);
        sf += __shfl_xor(sf, 32, 64);
        sg += __shfl_xor(sg, 32, 64);
        so += __shfl_xor(so, 32, 64);
        si += gi; sf += gf; sg += gg; so += go;
        c = fast_sig(sf) * c + fast_sig(si) * fast_tanh(sg);
        const float h = fast_sig(so) * fast_tanh(c);
        buf ^= 1;
        if (kh == 0) {
            hbuf[buf][j] = h;
            g_out[((size_t)b * T_DIM + t) * H_DIM + j] = h;
        }
        __syncthreads();
        gi = ngi; gf = ngf; gg = ngg; go = ngo;
    }
}

// Inference scan: one block (1 wave, 64 lanes) per batch row. All weights in registers.
// g layout [B,T,128], eps layout [T,B,16], z_out layout [B,T,16].
__global__ __launch_bounds__(64, 1) void infer_kernel(
    const float* __restrict__ g,
    const float* __restrict__ eps,
    const float* __restrict__ W_zg0, const float* __restrict__ b_zg0,
    const float* __restrict__ W_zg1, const float* __restrict__ b_zg1,
    const float* __restrict__ W_im,  const float* __restrict__ b_im,
    const float* __restrict__ W_il,  const float* __restrict__ b_il,
    float* __restrict__ z_out)
{
    __shared__ float zbuf[16];
    __shared__ float hzbuf[32];
    __shared__ float h2buf[128];
    const int l = threadIdx.x;
    const int b = blockIdx.x;

    // stage-1 weights: W_zg0 row (l&31), 16 wide
    const int r0 = l & 31;
    float4 wz0[4];
    #pragma unroll
    for (int q = 0; q < 4; ++q) wz0[q] = ((const float4*)W_zg0)[r0 * 4 + q];
    const float bz0 = b_zg0[r0];
    // stage-2 weights: W_zg1 rows l and l+64, 32 wide each
    float4 w1a[8], w1b[8];
    #pragma unroll
    for (int q = 0; q < 8; ++q) {
        w1a[q] = ((const float4*)W_zg1)[l * 8 + q];
        w1b[q] = ((const float4*)W_zg1)[(l + 64) * 8 + q];
    }
    const float bz1a = b_zg1[l], bz1b = b_zg1[l + 64];
    // stage-3 weights: output o=l&31 (o<16: zm row o; else zl row o-16), k half = l>>5
    const int o = l & 31;
    const int half = l >> 5;
    const float* w3p = (o < 16) ? (W_im + o * 128) : (W_il + (o - 16) * 128);
    float4 w3[16];
    #pragma unroll
    for (int q = 0; q < 16; ++q) w3[q] = ((const float4*)(w3p + half * 64))[q];
    const float b3 = (o < 16) ? b_im[o] : b_il[o - 16];

    if (l < 16) zbuf[l] = 0.0f;
    __syncthreads();

    const float* gb = g + (size_t)b * T_DIM * 128;
    float ngl0 = gb[l];
    float ngl1 = gb[64 + l];
    float neps = (l < 16) ? eps[(size_t)b * 16 + l] : 0.0f;
    for (int t = 0; t < T_DIM; ++t) {
        const float gl0 = ngl0, gl1 = ngl1, epsv = neps;
        if (t + 1 < T_DIM) {
            ngl0 = gb[(size_t)(t + 1) * 128 + l];
            ngl1 = gb[(size_t)(t + 1) * 128 + 64 + l];
            neps = (l < 16) ? eps[((size_t)(t + 1) * B_DIM + b) * 16 + l] : 0.0f;
        }
        // stage 1: hz = tanh(W_zg0 @ z + b_zg0), lanes 0..31
        float s1 = bz0;
        {
            const float4* z4 = (const float4*)zbuf;
            #pragma unroll
            for (int q = 0; q < 4; ++q) {
                const float4 zv = z4[q];
                s1 += wz0[q].x * zv.x + wz0[q].y * zv.y + wz0[q].z * zv.z + wz0[q].w * zv.w;
            }
        }
        const float hz = fast_tanh(s1);
        __syncthreads();
        if (l < 32) hzbuf[l] = hz;
        __syncthreads();
        // stage 2: hz2 = tanh(W_zg1 @ hz + b_zg1); g_t = 0.5*(hz2 + g_rnn)
        float s2a = bz1a, s2b = bz1b;
        {
            const float4* hz4 = (const float4*)hzbuf;
            #pragma unroll
            for (int q = 0; q < 8; ++q) {
                const float4 hv = hz4[q];
                s2a += w1a[q].x * hv.x + w1a[q].y * hv.y + w1a[q].z * hv.z + w1a[q].w * hv.w;
                s2b += w1b[q].x * hv.x + w1b[q].y * hv.y + w1b[q].z * hv.z + w1b[q].w * hv.w;
            }
        }
        const float gt0 = 0.5f * (fast_tanh(s2a) + gl0);
        const float gt1 = 0.5f * (fast_tanh(s2b) + gl1);
        __syncthreads();
        h2buf[l]      = gt0;
        h2buf[l + 64] = gt1;
        __syncthreads();
        // stage 3: zm/zl dot-128, split over lane pairs (l, l^32), outputs o=l&31
        float s3 = 0.0f;
        {
            const float4* h24 = (const float4*)(h2buf + half * 64);
            #pragma unroll
            for (int q = 0; q < 16; ++q) {
                const float4 hv = h24[q];
                s3 += w3[q].x * hv.x + w3[q].y * hv.y + w3[q].z * hv.z + w3[q].w * hv.w;
            }
        }
        const float full = s3 + __shfl_xor(s3, 32, 64);
        const float val = full + b3;                 // o<16: zm[o], o>=16: zl[o-16]
        const float other = __shfl_xor(val, 16, 64); // for l<16: zl[l]
        const float znew = val + epsv * __expf(0.5f * other);
        __syncthreads();
        if (l < 16) {
            zbuf[l] = znew;
            z_out[((size_t)b * T_DIM + t) * 16 + l] = znew;
        }
        __syncthreads();
    }
}

extern "C" void kernel_launch(void* const* d_in, const int* in_sizes, int n_in,
                              void* d_out, int out_size, void* d_ws, size_t ws_size,
                              hipStream_t stream)
{
    const float* x     = (const float*)d_in[0];
    const float* eps   = (const float*)d_in[1];
    const float* W_xg  = (const float*)d_in[2];
    const float* b_xg  = (const float*)d_in[3];
    const float* W_ih  = (const float*)d_in[4];
    const float* W_hh  = (const float*)d_in[5];
    const float* b_ih  = (const float*)d_in[6];
    const float* b_hh  = (const float*)d_in[7];
    const float* W_zg0 = (const float*)d_in[8];
    const float* b_zg0 = (const float*)d_in[9];
    const float* W_zg1 = (const float*)d_in[10];
    const float* b_zg1 = (const float*)d_in[11];
    const float* W_im  = (const float*)d_in[12];
    const float* b_im  = (const float*)d_in[13];
    const float* W_il  = (const float*)d_in[14];
    const float* b_il  = (const float*)d_in[15];
    // 16..27: gate/prop/pm/pl weights — dead code (outputs unused by reference return)
    const float* W_zx0 = (const float*)d_in[28];
    const float* b_zx0 = (const float*)d_in[29];
    const float* W_zx1 = (const float*)d_in[30];
    const float* b_zx1 = (const float*)d_in[31];
    const float* W_gy  = (const float*)d_in[32];
    const float* b_gy  = (const float*)d_in[33];
    float* out = (float*)d_out;
    float* ws  = (float*)d_ws;

    // workspace layout (floats)
    float* xg  = ws;                        // 131072*256 = 33,554,432
    float* gin = ws + 33554432ull;          // 131072*512 = 67,108,864
    float* g   = ws + 100663296ull;         // 131072*128 = 16,777,216
    float* z   = ws + 117440512ull;         // 131072*16  =  2,097,152
    float* bc  = ws + 119537664ull;         // 512
    float* hy1 = ws;                        // alias xg (dead after G2)
    float* hy2 = ws + 16777216ull;          // alias xg upper half

    bias_comb_kernel<<<1, 512, 0, stream>>>(b_ih, b_hh, bc);
    // G1: xg = tanh(xs @ W_xg.T + b_xg), m = b*T+t, A = x gather, K=513
    gemm_kernel<1, 1, 0, true><<<dim3(DX / 64, M_ROWS / 64), 256, 0, stream>>>(
        x, W_xg, b_xg, xg, M_ROWS, DX, F_DIM);
    // G2: gin = xg @ W_ih.T + (b_ih + b_hh), K=256, N=512
    gemm_kernel<0, 0, 0, false><<<dim3(G4 / 64, M_ROWS / 64), 256, 0, stream>>>(
        xg, W_ih, bc, gin, M_ROWS, G4, DX);
    // backward LSTM scan -> g
    lstm_kernel<<<B_DIM, 256, 0, stream>>>(gin, W_hh, g);
    // inference scan -> z
    infer_kernel<<<B_DIM, 64, 0, stream>>>(g, eps, W_zg0, b_zg0, W_zg1, b_zg1,
                                           W_im, b_im, W_il, b_il, z);
    // y path
    gemm_kernel<1, 0, 0, false><<<dim3(DZX_D / 64, M_ROWS / 64), 256, 0, stream>>>(
        z, W_zx0, b_zx0, hy1, M_ROWS, DZX_D, Z_DIM);
    gemm_kernel<1, 0, 0, false><<<dim3(DZX_D / 64, M_ROWS / 64), 256, 0, stream>>>(
        hy1, W_zx1, b_zx1, hy2, M_ROWS, DZX_D, DZX_D);
    gemm_kernel<2, 0, 1, true><<<dim3(9, M_ROWS / 64), 256, 0, stream>>>(
        hy2, W_gy, b_gy, out, M_ROWS, F_DIM, DZX_D);
}

// Round 3
// 3046.746 us; speedup vs baseline: 1.0913x; 1.0774x over previous
//
#include <hip/hip_runtime.h>
#include <cstdint>

#define T_DIM 512
#define B_DIM 256
#define F_DIM 513
#define DX    256
#define H_DIM 128
#define G4    512
#define Z_DIM 16
#define ZG_D  32
#define DZX_D 128
#define M_ROWS (B_DIM * T_DIM)   // 131072

__device__ __forceinline__ float fast_tanh(float x) {
    return 1.0f - 2.0f / (__expf(2.0f * x) + 1.0f);
}
__device__ __forceinline__ float fast_sig(float x) {
    return 1.0f / (1.0f + __expf(-x));
}

__global__ void bias_comb_kernel(const float* __restrict__ a,
                                 const float* __restrict__ b,
                                 float* __restrict__ c) {
    int i = threadIdx.x;
    if (i < G4) c[i] = a[i] + b[i];
}

// Generic tiled fp32 GEMM:  C[m,n] = act(sum_k A[m,k] * W[n,k] + bias[n])
// ACT: 0 none, 1 tanh, 2 exp
// AMODE: 0 contiguous row-major [M,K] (requires K%16==0), 1 x-gather A[m,k]=x[b,k,t], m=b*T+t
// CMODE: 0 contiguous [M,N], 1 transposed out[b,n,t]
// GUARD: scalar+bounds-guarded W loads (K edge or N edge)
template<int ACT, int AMODE, int CMODE, bool GUARD>
__global__ __launch_bounds__(256) void gemm_kernel(
    const float* __restrict__ A, const float* __restrict__ W,
    const float* __restrict__ bias, float* __restrict__ C,
    int M, int N, int K)
{
    __shared__ float As[16][68];
    __shared__ float Bs[16][68];
    const int tid = threadIdx.x;
    const int m0 = blockIdx.y * 64;
    const int n0 = blockIdx.x * 64;
    const int tm = tid >> 4;   // 0..15
    const int tn = tid & 15;   // 0..15
    float acc[4][4] = {};
    const int kTiles = (K + 15) >> 4;
    for (int kt = 0; kt < kTiles; ++kt) {
        const int k0 = kt << 4;
        // ---- load A tile (transposed into LDS: As[k][m]) ----
        if (AMODE == 0) {
            const int m  = tid >> 2;      // 0..63
            const int kq = tid & 3;       // 0..3
            const float4 v = *(const float4*)&A[(size_t)(m0 + m) * K + k0 + kq * 4];
            As[kq * 4 + 0][m] = v.x; As[kq * 4 + 1][m] = v.y;
            As[kq * 4 + 2][m] = v.z; As[kq * 4 + 3][m] = v.w;
        } else {
            const int m  = tid & 63;
            const int kq = tid >> 6;      // 0..3
            const int mg = m0 + m;
            const int bb = mg >> 9;       // /T
            const int tt = mg & 511;      // %T
            const size_t base = (size_t)bb * (F_DIM * T_DIM) + tt;
            #pragma unroll
            for (int j = 0; j < 4; ++j) {
                const int k = k0 + kq * 4 + j;
                As[kq * 4 + j][m] = (k < K) ? A[base + (size_t)k * T_DIM] : 0.0f;
            }
        }
        // ---- load W tile (Bs[k][n]) ----
        {
            const int n  = tid >> 2;
            const int kq = tid & 3;
            const int ng = n0 + n;
            if (!GUARD) {
                const float4 v = *(const float4*)&W[(size_t)ng * K + k0 + kq * 4];
                Bs[kq * 4 + 0][n] = v.x; Bs[kq * 4 + 1][n] = v.y;
                Bs[kq * 4 + 2][n] = v.z; Bs[kq * 4 + 3][n] = v.w;
            } else {
                #pragma unroll
                for (int j = 0; j < 4; ++j) {
                    const int k = k0 + kq * 4 + j;
                    float v = 0.0f;
                    if (ng < N && k < K) v = W[(size_t)ng * K + k];
                    Bs[kq * 4 + j][n] = v;
                }
            }
        }
        __syncthreads();
        #pragma unroll
        for (int kk = 0; kk < 16; ++kk) {
            const float4 av = *(const float4*)&As[kk][tm * 4];
            const float4 bv = *(const float4*)&Bs[kk][tn * 4];
            const float a0 = av.x, a1 = av.y, a2 = av.z, a3 = av.w;
            const float b0 = bv.x, b1 = bv.y, b2 = bv.z, b3 = bv.w;
            acc[0][0] += a0 * b0; acc[0][1] += a0 * b1; acc[0][2] += a0 * b2; acc[0][3] += a0 * b3;
            acc[1][0] += a1 * b0; acc[1][1] += a1 * b1; acc[1][2] += a1 * b2; acc[1][3] += a1 * b3;
            acc[2][0] += a2 * b0; acc[2][1] += a2 * b1; acc[2][2] += a2 * b2; acc[2][3] += a2 * b3;
            acc[3][0] += a3 * b0; acc[3][1] += a3 * b1; acc[3][2] += a3 * b2; acc[3][3] += a3 * b3;
        }
        __syncthreads();
    }
    // ---- epilogue ----
    #pragma unroll
    for (int i = 0; i < 4; ++i) {
        const int m = m0 + tm * 4 + i;
        if (CMODE == 0) {
            float r[4];
            #pragma unroll
            for (int j = 0; j < 4; ++j) {
                const int n = n0 + tn * 4 + j;
                float v = acc[i][j] + bias[n];
                if (ACT == 1) v = fast_tanh(v);
                else if (ACT == 2) v = __expf(v);
                r[j] = v;
            }
            *(float4*)&C[(size_t)m * N + n0 + tn * 4] = make_float4(r[0], r[1], r[2], r[3]);
        } else {
            const int bb = m >> 9;
            const int tt = m & 511;
            #pragma unroll
            for (int j = 0; j < 4; ++j) {
                const int n = n0 + tn * 4 + j;
                if (n < N) {
                    float v = acc[i][j] + bias[n];
                    if (ACT == 1) v = fast_tanh(v);
                    else if (ACT == 2) v = __expf(v);
                    C[(size_t)bb * (F_DIM * T_DIM) + (size_t)n * T_DIM + tt] = v;
                }
            }
        }
    }
}

#define PIN4(v) asm volatile("" : "+v"((v).x), "+v"((v).y), "+v"((v).z), "+v"((v).w))

// Backward LSTM: one block per batch row b, 512 threads (8 waves).
// Thread (wave w, lane l): h-index j = w*16 + (l&15), K-quarter kq = l>>4.
// Per-thread weights: 4 gates x 32 K-elems = 128 VGPRs (PINned so the compiler
// cannot re-sink the loads into the t-loop — round-2 defect, VGPR_Count 152 < 256).
// Cross-kq combine: shfl_xor 16 + 32 (in-wave). Double-buffered LDS h, ONE
// barrier per step. gin layout [B,T,512] (biases folded), g_out [B,T,128].
__global__ __launch_bounds__(512, 2) void lstm_kernel(
    const float* __restrict__ gin,
    const float* __restrict__ W_hh,   // [512,128] row-major
    float* __restrict__ g_out)
{
    __shared__ float hbuf[2][128];
    const int tid  = threadIdx.x;
    const int b    = blockIdx.x;
    const int lane = tid & 63;
    const int w    = tid >> 6;             // wave 0..7
    const int j    = w * 16 + (lane & 15); // h index 0..127
    const int kq   = lane >> 4;            // K-quarter 0..3

    // weights: rows j, j+128, j+256, j+384, float4 cols [kq*8, kq*8+8)
    float4 wi[8], wf[8], wg[8], wo[8];
    {
        const float4* w4 = (const float4*)W_hh;
        const int cb = kq * 8;
        #pragma unroll
        for (int q = 0; q < 8; ++q) {
            wi[q] = w4[(size_t)(j      ) * 32 + cb + q];
            wf[q] = w4[(size_t)(j + 128) * 32 + cb + q];
            wg[q] = w4[(size_t)(j + 256) * 32 + cb + q];
            wo[q] = w4[(size_t)(j + 384) * 32 + cb + q];
        }
        #pragma unroll
        for (int q = 0; q < 8; ++q) { PIN4(wi[q]); PIN4(wf[q]); PIN4(wg[q]); PIN4(wo[q]); }
    }
    if (tid < 128) { hbuf[0][tid] = 0.f; hbuf[1][tid] = 0.f; }
    float c = 0.0f;
    __syncthreads();

    const float* ginb = gin + (size_t)b * T_DIM * G4;
    float gi = ginb[(size_t)(T_DIM - 1) * G4 + j];
    float gf = ginb[(size_t)(T_DIM - 1) * G4 + j + 128];
    float gg = ginb[(size_t)(T_DIM - 1) * G4 + j + 256];
    float go = ginb[(size_t)(T_DIM - 1) * G4 + j + 384];

    int buf = 0;
    for (int t = T_DIM - 1; t >= 0; --t) {
        float ngi = 0.f, ngf = 0.f, ngg = 0.f, ngo = 0.f;
        if (t > 0) {
            const size_t base = (size_t)(t - 1) * G4;
            ngi = ginb[base + j];
            ngf = ginb[base + j + 128];
            ngg = ginb[base + j + 256];
            ngo = ginb[base + j + 384];
        }
        float si = 0.f, sf = 0.f, sg = 0.f, so = 0.f;
        {
            const float4* h4 = (const float4*)&hbuf[buf][kq * 32];
            #pragma unroll
            for (int q = 0; q < 8; ++q) {
                const float4 hv = h4[q];
                si += wi[q].x * hv.x + wi[q].y * hv.y + wi[q].z * hv.z + wi[q].w * hv.w;
                sf += wf[q].x * hv.x + wf[q].y * hv.y + wf[q].z * hv.z + wf[q].w * hv.w;
                sg += wg[q].x * hv.x + wg[q].y * hv.y + wg[q].z * hv.z + wg[q].w * hv.w;
                so += wo[q].x * hv.x + wo[q].y * hv.y + wo[q].z * hv.z + wo[q].w * hv.w;
            }
        }
        si += __shfl_xor(si, 16, 64); si += __shfl_xor(si, 32, 64);
        sf += __shfl_xor(sf, 16, 64); sf += __shfl_xor(sf, 32, 64);
        sg += __shfl_xor(sg, 16, 64); sg += __shfl_xor(sg, 32, 64);
        so += __shfl_xor(so, 16, 64); so += __shfl_xor(so, 32, 64);
        si += gi; sf += gf; sg += gg; so += go;
        c = fast_sig(sf) * c + fast_sig(si) * fast_tanh(sg);
        const float h = fast_sig(so) * fast_tanh(c);
        buf ^= 1;
        if (kq == 0) {
            hbuf[buf][j] = h;
            g_out[((size_t)b * T_DIM + t) * H_DIM + j] = h;
        }
        __syncthreads();
        gi = ngi; gf = ngf; gg = ngg; go = ngo;
    }
}

// Inference scan: one block (1 wave, 64 lanes) per batch row. All weights in registers.
// g layout [B,T,128], eps layout [T,B,16], z_out layout [B,T,16].
__global__ __launch_bounds__(64, 1) void infer_kernel(
    const float* __restrict__ g,
    const float* __restrict__ eps,
    const float* __restrict__ W_zg0, const float* __restrict__ b_zg0,
    const float* __restrict__ W_zg1, const float* __restrict__ b_zg1,
    const float* __restrict__ W_im,  const float* __restrict__ b_im,
    const float* __restrict__ W_il,  const float* __restrict__ b_il,
    float* __restrict__ z_out)
{
    __shared__ float zbuf[16];
    __shared__ float hzbuf[32];
    __shared__ float h2buf[128];
    const int l = threadIdx.x;
    const int b = blockIdx.x;

    // stage-1 weights: W_zg0 row (l&31), 16 wide
    const int r0 = l & 31;
    float4 wz0[4];
    #pragma unroll
    for (int q = 0; q < 4; ++q) wz0[q] = ((const float4*)W_zg0)[r0 * 4 + q];
    const float bz0 = b_zg0[r0];
    // stage-2 weights: W_zg1 rows l and l+64, 32 wide each
    float4 w1a[8], w1b[8];
    #pragma unroll
    for (int q = 0; q < 8; ++q) {
        w1a[q] = ((const float4*)W_zg1)[l * 8 + q];
        w1b[q] = ((const float4*)W_zg1)[(l + 64) * 8 + q];
    }
    const float bz1a = b_zg1[l], bz1b = b_zg1[l + 64];
    // stage-3 weights: output o=l&31 (o<16: zm row o; else zl row o-16), k half = l>>5
    const int o = l & 31;
    const int half = l >> 5;
    const float* w3p = (o < 16) ? (W_im + o * 128) : (W_il + (o - 16) * 128);
    float4 w3[16];
    #pragma unroll
    for (int q = 0; q < 16; ++q) w3[q] = ((const float4*)(w3p + half * 64))[q];
    const float b3 = (o < 16) ? b_im[o] : b_il[o - 16];

    if (l < 16) zbuf[l] = 0.0f;
    __syncthreads();

    const float* gb = g + (size_t)b * T_DIM * 128;
    float ngl0 = gb[l];
    float ngl1 = gb[64 + l];
    float neps = (l < 16) ? eps[(size_t)b * 16 + l] : 0.0f;
    for (int t = 0; t < T_DIM; ++t) {
        const float gl0 = ngl0, gl1 = ngl1, epsv = neps;
        if (t + 1 < T_DIM) {
            ngl0 = gb[(size_t)(t + 1) * 128 + l];
            ngl1 = gb[(size_t)(t + 1) * 128 + 64 + l];
            neps = (l < 16) ? eps[((size_t)(t + 1) * B_DIM + b) * 16 + l] : 0.0f;
        }
        // stage 1: hz = tanh(W_zg0 @ z + b_zg0), lanes 0..31
        float s1 = bz0;
        {
            const float4* z4 = (const float4*)zbuf;
            #pragma unroll
            for (int q = 0; q < 4; ++q) {
                const float4 zv = z4[q];
                s1 += wz0[q].x * zv.x + wz0[q].y * zv.y + wz0[q].z * zv.z + wz0[q].w * zv.w;
            }
        }
        const float hz = fast_tanh(s1);
        __syncthreads();
        if (l < 32) hzbuf[l] = hz;
        __syncthreads();
        // stage 2: hz2 = tanh(W_zg1 @ hz + b_zg1); g_t = 0.5*(hz2 + g_rnn)
        float s2a = bz1a, s2b = bz1b;
        {
            const float4* hz4 = (const float4*)hzbuf;
            #pragma unroll
            for (int q = 0; q < 8; ++q) {
                const float4 hv = hz4[q];
                s2a += w1a[q].x * hv.x + w1a[q].y * hv.y + w1a[q].z * hv.z + w1a[q].w * hv.w;
                s2b += w1b[q].x * hv.x + w1b[q].y * hv.y + w1b[q].z * hv.z + w1b[q].w * hv.w;
            }
        }
        const float gt0 = 0.5f * (fast_tanh(s2a) + gl0);
        const float gt1 = 0.5f * (fast_tanh(s2b) + gl1);
        __syncthreads();
        h2buf[l]      = gt0;
        h2buf[l + 64] = gt1;
        __syncthreads();
        // stage 3: zm/zl dot-128, split over lane pairs (l, l^32), outputs o=l&31
        float s3 = 0.0f;
        {
            const float4* h24 = (const float4*)(h2buf + half * 64);
            #pragma unroll
            for (int q = 0; q < 16; ++q) {
                const float4 hv = h24[q];
                s3 += w3[q].x * hv.x + w3[q].y * hv.y + w3[q].z * hv.z + w3[q].w * hv.w;
            }
        }
        const float full = s3 + __shfl_xor(s3, 32, 64);
        const float val = full + b3;                 // o<16: zm[o], o>=16: zl[o-16]
        const float other = __shfl_xor(val, 16, 64); // for l<16: zl[l]
        const float znew = val + epsv * __expf(0.5f * other);
        __syncthreads();
        if (l < 16) {
            zbuf[l] = znew;
            z_out[((size_t)b * T_DIM + t) * 16 + l] = znew;
        }
        __syncthreads();
    }
}

extern "C" void kernel_launch(void* const* d_in, const int* in_sizes, int n_in,
                              void* d_out, int out_size, void* d_ws, size_t ws_size,
                              hipStream_t stream)
{
    const float* x     = (const float*)d_in[0];
    const float* eps   = (const float*)d_in[1];
    const float* W_xg  = (const float*)d_in[2];
    const float* b_xg  = (const float*)d_in[3];
    const float* W_ih  = (const float*)d_in[4];
    const float* W_hh  = (const float*)d_in[5];
    const float* b_ih  = (const float*)d_in[6];
    const float* b_hh  = (const float*)d_in[7];
    const float* W_zg0 = (const float*)d_in[8];
    const float* b_zg0 = (const float*)d_in[9];
    const float* W_zg1 = (const float*)d_in[10];
    const float* b_zg1 = (const float*)d_in[11];
    const float* W_im  = (const float*)d_in[12];
    const float* b_im  = (const float*)d_in[13];
    const float* W_il  = (const float*)d_in[14];
    const float* b_il  = (const float*)d_in[15];
    // 16..27: gate/prop/pm/pl weights — dead code (outputs unused by reference return)
    const float* W_zx0 = (const float*)d_in[28];
    const float* b_zx0 = (const float*)d_in[29];
    const float* W_zx1 = (const float*)d_in[30];
    const float* b_zx1 = (const float*)d_in[31];
    const float* W_gy  = (const float*)d_in[32];
    const float* b_gy  = (const float*)d_in[33];
    float* out = (float*)d_out;
    float* ws  = (float*)d_ws;

    // workspace layout (floats)
    float* xg  = ws;                        // 131072*256 = 33,554,432
    float* gin = ws + 33554432ull;          // 131072*512 = 67,108,864
    float* g   = ws + 100663296ull;         // 131072*128 = 16,777,216
    float* z   = ws + 117440512ull;         // 131072*16  =  2,097,152
    float* bc  = ws + 119537664ull;         // 512
    float* hy1 = ws;                        // alias xg (dead after G2)
    float* hy2 = ws + 16777216ull;          // alias xg upper half

    bias_comb_kernel<<<1, 512, 0, stream>>>(b_ih, b_hh, bc);
    // G1: xg = tanh(xs @ W_xg.T + b_xg), m = b*T+t, A = x gather, K=513
    gemm_kernel<1, 1, 0, true><<<dim3(DX / 64, M_ROWS / 64), 256, 0, stream>>>(
        x, W_xg, b_xg, xg, M_ROWS, DX, F_DIM);
    // G2: gin = xg @ W_ih.T + (b_ih + b_hh), K=256, N=512
    gemm_kernel<0, 0, 0, false><<<dim3(G4 / 64, M_ROWS / 64), 256, 0, stream>>>(
        xg, W_ih, bc, gin, M_ROWS, G4, DX);
    // backward LSTM scan -> g
    lstm_kernel<<<B_DIM, 512, 0, stream>>>(gin, W_hh, g);
    // inference scan -> z
    infer_kernel<<<B_DIM, 64, 0, stream>>>(g, eps, W_zg0, b_zg0, W_zg1, b_zg1,
                                           W_im, b_im, W_il, b_il, z);
    // y path
    gemm_kernel<1, 0, 0, false><<<dim3(DZX_D / 64, M_ROWS / 64), 256, 0, stream>>>(
        z, W_zx0, b_zx0, hy1, M_ROWS, DZX_D, Z_DIM);
    gemm_kernel<1, 0, 0, false><<<dim3(DZX_D / 64, M_ROWS / 64), 256, 0, stream>>>(
        hy1, W_zx1, b_zx1, hy2, M_ROWS, DZX_D, DZX_D);
    gemm_kernel<2, 0, 1, true><<<dim3(9, M_ROWS / 64), 256, 0, stream>>>(
        hy2, W_gy, b_gy, out, M_ROWS, F_DIM, DZX_D);
}